// Round 3
// baseline (2512.183 us; speedup 1.0000x reference)
//
#include <hip/hip_runtime.h>

#define N_NODES 100000
#define D_FEAT  64
#define N_EDGES 1600000
#define NPB     128                         // nodes per bucket (dst >> 7)
#define NBUCK   ((N_NODES + NPB - 1) / NPB) // 782

// ---------------- coarse bucket build ----------------

// per-block LDS histogram of dst>>7, flushed with one atomic per bucket
__global__ void hist_bucket(const int* __restrict__ dst, int* __restrict__ bcount) {
    __shared__ int h[NBUCK];
    for (int i = threadIdx.x; i < NBUCK; i += blockDim.x) h[i] = 0;
    __syncthreads();
    int i = blockIdx.x * blockDim.x + threadIdx.x;
    int stride = gridDim.x * blockDim.x;
    for (; i < N_EDGES; i += stride)
        atomicAdd(&h[dst[i] >> 7], 1);
    __syncthreads();
    for (int i = threadIdx.x; i < NBUCK; i += blockDim.x)
        if (h[i]) atomicAdd(&bcount[i], h[i]);
}

// single-block Hillis-Steele exclusive scan of 782 bucket counts
__global__ void scan_buckets(const int* __restrict__ bcount, int* __restrict__ bptr,
                             int* __restrict__ cursor) {
    __shared__ int tmp[1024];
    int t = threadIdx.x;
    int v0 = (t < NBUCK) ? bcount[t] : 0;
    tmp[t] = v0;
    __syncthreads();
    for (int off = 1; off < 1024; off <<= 1) {
        int v = (t >= off) ? tmp[t - off] : 0;
        __syncthreads();
        tmp[t] += v;
        __syncthreads();
    }
    if (t < NBUCK) {
        int ex = tmp[t] - v0;
        bptr[t] = ex;
        cursor[t] = ex;
    }
    if (t == 0) bptr[NBUCK] = N_EDGES;
}

// append edges to their bucket region; packed word = src | (dst&127)<<17
__global__ void scatter_bucket(const int* __restrict__ src, const int* __restrict__ dst,
                               const float* __restrict__ ew, int* __restrict__ cursor,
                               int2* __restrict__ bedges) {
    int i = blockIdx.x * blockDim.x + threadIdx.x;
    int stride = gridDim.x * blockDim.x;
    for (; i < N_EDGES; i += stride) {
        int d = dst[i];
        int b = d >> 7;
        int p = atomicAdd(&cursor[b], 1);
        int2 e;
        e.x = src[i] | ((d & (NPB - 1)) << 17);
        e.y = __float_as_int(ew[i]);
        bedges[p] = e;
    }
}

// ---------------- bucketed SpMM with LDS accumulation ----------------
// One block per bucket; 32 KB LDS tile (128 nodes x 64 feats).
// Wave processes edges in chunks of 8 for gather ILP; lane = feature.
// MODE 0: out = X + h (write h) | MODE 1: out += h (write h) | MODE 2: out = (out+h)/4
template <int MODE>
__global__ __launch_bounds__(512) void spmm_bucket(const float* __restrict__ hprev,
                                                   const int* __restrict__ bptr,
                                                   const int2* __restrict__ bedges,
                                                   float* __restrict__ hout,
                                                   float* __restrict__ out,
                                                   const float* __restrict__ X) {
    __shared__ float acc[NPB * D_FEAT];   // 32 KB
    const int b    = blockIdx.x;
    const int lane = threadIdx.x & 63;
    const int wid  = threadIdx.x >> 6;    // 0..7
    const int nw   = blockDim.x >> 6;     // 8

    for (int i = threadIdx.x; i < NPB * D_FEAT; i += blockDim.x) acc[i] = 0.0f;
    __syncthreads();

    const int beg = bptr[b];
    const int end = bptr[b + 1];

    for (int e0 = beg + (wid << 3); e0 < end; e0 += (nw << 3)) {
        int cnt = end - e0;
        if (cnt > 8) cnt = 8;
        int2 ed[8];
        #pragma unroll
        for (int k = 0; k < 8; ++k)
            if (k < cnt) ed[k] = bedges[e0 + k];
        float v[8];
        int   dl[8];
        #pragma unroll
        for (int k = 0; k < 8; ++k)
            if (k < cnt) {
                int s  = ed[k].x & 0x1FFFF;
                dl[k]  = ed[k].x >> 17;
                v[k]   = hprev[((size_t)s << 6) | lane] * __int_as_float(ed[k].y);
            }
        #pragma unroll
        for (int k = 0; k < 8; ++k)
            if (k < cnt) atomicAdd(&acc[(dl[k] << 6) | lane], v[k]);
    }
    __syncthreads();

    // coalesced float4 writeback, layer-sum fused into out
    const float4* a4 = (const float4*)acc;
    const int base4  = b * (NPB * D_FEAT / 4);          // block's first float4 index
    const int tot4   = N_NODES * D_FEAT / 4;            // global float4 count
    for (int i = threadIdx.x; i < NPB * D_FEAT / 4; i += blockDim.x) {
        int g = base4 + i;
        if (g >= tot4) break;
        float4 h = a4[i];
        if (MODE == 0) {
            float4 x = ((const float4*)X)[g];
            ((float4*)hout)[g] = h;
            float4 r; r.x = x.x + h.x; r.y = x.y + h.y; r.z = x.z + h.z; r.w = x.w + h.w;
            ((float4*)out)[g] = r;
        } else if (MODE == 1) {
            float4 o = ((float4*)out)[g];
            ((float4*)hout)[g] = h;
            o.x += h.x; o.y += h.y; o.z += h.z; o.w += h.w;
            ((float4*)out)[g] = o;
        } else {
            float4 o = ((float4*)out)[g];
            o.x = (o.x + h.x) * 0.25f; o.y = (o.y + h.y) * 0.25f;
            o.z = (o.z + h.z) * 0.25f; o.w = (o.w + h.w) * 0.25f;
            ((float4*)out)[g] = o;
        }
    }
}

extern "C" void kernel_launch(void* const* d_in, const int* in_sizes, int n_in,
                              void* d_out, int out_size, void* d_ws, size_t ws_size,
                              hipStream_t stream) {
    const float* X   = (const float*)d_in[0];
    const int*   src = (const int*)  d_in[1];
    const int*   dst = (const int*)  d_in[2];
    const float* ew  = (const float*)d_in[3];
    float* out = (float*)d_out;

    const size_t feat = (size_t)N_NODES * D_FEAT;

    char* p = (char*)d_ws;
    float* hA     = (float*)p;  p += feat * sizeof(float);        // 25.6 MB
    float* hB     = (float*)p;  p += feat * sizeof(float);        // 25.6 MB
    int2*  bedges = (int2*)p;   p += (size_t)N_EDGES * 8;         // 12.8 MB
    int*   bcount = (int*)p;    p += (size_t)NBUCK * 4;
    int*   bptr   = (int*)p;    p += ((size_t)NBUCK + 1) * 4;
    int*   cursor = (int*)p;    p += (size_t)NBUCK * 4;

    hipMemsetAsync(bcount, 0, (size_t)NBUCK * sizeof(int), stream);

    hist_bucket<<<256, 256, 0, stream>>>(dst, bcount);
    scan_buckets<<<1, 1024, 0, stream>>>(bcount, bptr, cursor);
    scatter_bucket<<<1024, 256, 0, stream>>>(src, dst, ew, cursor, bedges);

    spmm_bucket<0><<<NBUCK, 512, 0, stream>>>(X,  bptr, bedges, hA, out, X);
    spmm_bucket<1><<<NBUCK, 512, 0, stream>>>(hA, bptr, bedges, hB, out, X);
    spmm_bucket<2><<<NBUCK, 512, 0, stream>>>(hB, bptr, bedges, (float*)nullptr, out, X);
}

// Round 4
// 797.187 us; speedup vs baseline: 3.1513x; 3.1513x over previous
//
#include <hip/hip_runtime.h>

#define N_NODES 100000
#define D_FEAT  64
#define N_EDGES 1600000
#define NPB     128                         // nodes per bucket (dst >> 7)
#define NBUCK   ((N_NODES + NPB - 1) / NPB) // 782

// ---------------- phase 1: coarse bucket histogram ----------------
__global__ void hist_bucket(const int* __restrict__ dst, int* __restrict__ bcount) {
    __shared__ int h[NBUCK];
    for (int i = threadIdx.x; i < NBUCK; i += blockDim.x) h[i] = 0;
    __syncthreads();
    int i = blockIdx.x * blockDim.x + threadIdx.x;
    int stride = gridDim.x * blockDim.x;
    for (; i < N_EDGES; i += stride)
        atomicAdd(&h[dst[i] >> 7], 1);
    __syncthreads();
    for (int i = threadIdx.x; i < NBUCK; i += blockDim.x)
        if (h[i]) atomicAdd(&bcount[i], h[i]);
}

// ---------------- phase 2: scan 782 bucket counts ----------------
__global__ void scan_buckets(const int* __restrict__ bcount, int* __restrict__ bptr,
                             int* __restrict__ cursor, int* __restrict__ row_ptr) {
    __shared__ int tmp[1024];
    int t = threadIdx.x;
    int v0 = (t < NBUCK) ? bcount[t] : 0;
    tmp[t] = v0;
    __syncthreads();
    for (int off = 1; off < 1024; off <<= 1) {
        int v = (t >= off) ? tmp[t - off] : 0;
        __syncthreads();
        tmp[t] += v;
        __syncthreads();
    }
    if (t < NBUCK) {
        int ex = tmp[t] - v0;
        bptr[t] = ex;
        cursor[t] = ex;
    }
    if (t == 0) {
        bptr[NBUCK] = N_EDGES;
        row_ptr[N_NODES] = N_EDGES;
    }
}

// ---------------- phase 3: coarse scatter (L2-resident frontier) ----------------
// packed word = src | (dst & 127) << 17   (src < 2^17)
__global__ void scatter_bucket(const int* __restrict__ src, const int* __restrict__ dst,
                               const float* __restrict__ ew, int* __restrict__ cursor,
                               int2* __restrict__ bedges) {
    int i = blockIdx.x * blockDim.x + threadIdx.x;
    int stride = gridDim.x * blockDim.x;
    for (; i < N_EDGES; i += stride) {
        int d = dst[i];
        int b = d >> 7;
        int p = atomicAdd(&cursor[b], 1);
        int2 e;
        e.x = src[i] | ((d & (NPB - 1)) << 17);
        e.y = __float_as_int(ew[i]);
        bedges[p] = e;
    }
}

// ---------------- phase 4: per-bucket LDS counting sort -> dst-sorted edges + row_ptr
__global__ void sort_bucket(const int2* __restrict__ bedges, const int* __restrict__ bptr,
                            int2* __restrict__ sedges, int* __restrict__ row_ptr) {
    __shared__ int cnt[NPB];
    __shared__ int sc[NPB];
    __shared__ int cur[NPB];
    const int b = blockIdx.x;
    const int t = threadIdx.x;
    const int beg = bptr[b];
    const int end = bptr[b + 1];

    if (t < NPB) cnt[t] = 0;
    __syncthreads();
    for (int i = beg + t; i < end; i += blockDim.x)
        atomicAdd(&cnt[bedges[i].x >> 17], 1);
    __syncthreads();

    // inclusive Hillis-Steele over 128 entries
    if (t < NPB) sc[t] = cnt[t];
    __syncthreads();
    for (int off = 1; off < NPB; off <<= 1) {
        int v = (t >= off && t < NPB) ? sc[t - off] : 0;
        __syncthreads();
        if (t < NPB) sc[t] += v;
        __syncthreads();
    }
    if (t < NPB) {
        int ex = sc[t] - cnt[t];
        cur[t] = ex;
        int node = b * NPB + t;
        if (node < N_NODES) row_ptr[node] = beg + ex;
    }
    __syncthreads();

    for (int i = beg + t; i < end; i += blockDim.x) {
        int2 e = bedges[i];
        int dl = e.x >> 17;
        int p = atomicAdd(&cur[dl], 1);
        int2 o;
        o.x = e.x & 0x1FFFF;   // src
        o.y = e.y;             // weight
        sedges[beg + p] = o;
    }
}

// ---------------- phase 5: pull SpMM, 8-grouped gathers ----------------
// One 64-lane wave per destination node; lane = feature.
// MODE 0: out = X + h (write h) | MODE 1: out += h (write h) | MODE 2: out = (out+h)/4
template <int MODE>
__global__ void spmm_pull(const float* __restrict__ hprev,
                          const int* __restrict__ row_ptr,
                          const int2* __restrict__ edges,
                          float* __restrict__ hout,
                          float* __restrict__ acc,
                          const float* __restrict__ X) {
    int node = blockIdx.x * (blockDim.x >> 6) + (threadIdx.x >> 6);
    int lane = threadIdx.x & 63;
    if (node >= N_NODES) return;

    int beg = row_ptr[node];
    int end = row_ptr[node + 1];

    float a = 0.0f;
    for (int base = beg; base < end; base += 64) {
        int n = end - base;
        if (n > 64) n = 64;
        int s = 0;
        float w = 0.0f;
        if (lane < n) {
            int2 e = edges[base + lane];
            s = e.x;
            w = __int_as_float(e.y);
        }
        // groups of 8 independent gathers (wave-uniform predicates only)
        for (int j0 = 0; j0 < n; j0 += 8) {
            float t[8], ww[8];
            #pragma unroll
            for (int k = 0; k < 8; ++k) {
                int idx = j0 + k;
                if (idx < n) {                       // wave-uniform
                    int sj = __shfl(s, idx);
                    ww[k]  = __shfl(w, idx);
                    t[k]   = hprev[((size_t)sj << 6) | lane];
                } else {
                    ww[k] = 0.0f; t[k] = 0.0f;
                }
            }
            #pragma unroll
            for (int k = 0; k < 8; ++k)
                a += t[k] * ww[k];
        }
    }

    size_t idx = ((size_t)node << 6) | lane;
    if (MODE == 0) {
        hout[idx] = a;
        acc[idx] = X[idx] + a;
    } else if (MODE == 1) {
        hout[idx] = a;
        acc[idx] += a;
    } else {
        acc[idx] = (acc[idx] + a) * 0.25f;
    }
}

extern "C" void kernel_launch(void* const* d_in, const int* in_sizes, int n_in,
                              void* d_out, int out_size, void* d_ws, size_t ws_size,
                              hipStream_t stream) {
    const float* X   = (const float*)d_in[0];
    const int*   src = (const int*)  d_in[1];
    const int*   dst = (const int*)  d_in[2];
    const float* ew  = (const float*)d_in[3];
    float* out = (float*)d_out;

    const size_t feat = (size_t)N_NODES * D_FEAT;

    char* p = (char*)d_ws;
    float* hA      = (float*)p;  p += feat * sizeof(float);        // 25.6 MB
    float* hB      = (float*)p;  p += feat * sizeof(float);        // 25.6 MB
    int2*  bedges  = (int2*)p;   p += (size_t)N_EDGES * 8;         // 12.8 MB
    int2*  sedges  = (int2*)p;   p += (size_t)N_EDGES * 8;         // 12.8 MB
    int*   bcount  = (int*)p;    p += (size_t)NBUCK * 4;
    int*   bptr    = (int*)p;    p += ((size_t)NBUCK + 1) * 4;
    int*   cursor  = (int*)p;    p += (size_t)NBUCK * 4;
    int*   row_ptr = (int*)p;    p += ((size_t)N_NODES + 1) * 4;

    hipMemsetAsync(bcount, 0, (size_t)NBUCK * sizeof(int), stream);

    hist_bucket<<<256, 256, 0, stream>>>(dst, bcount);
    scan_buckets<<<1, 1024, 0, stream>>>(bcount, bptr, cursor, row_ptr);
    scatter_bucket<<<1024, 256, 0, stream>>>(src, dst, ew, cursor, bedges);
    sort_bucket<<<NBUCK, 256, 0, stream>>>(bedges, bptr, sedges, row_ptr);

    const int nblk = (N_NODES + 3) / 4;   // 4 waves/block
    spmm_pull<0><<<nblk, 256, 0, stream>>>(X,  row_ptr, sedges, hA, out, X);
    spmm_pull<1><<<nblk, 256, 0, stream>>>(hA, row_ptr, sedges, hB, out, X);
    spmm_pull<2><<<nblk, 256, 0, stream>>>(hB, row_ptr, sedges, (float*)nullptr, out, X);
}

// Round 5
// 478.027 us; speedup vs baseline: 5.2553x; 1.6677x over previous
//
#include <hip/hip_runtime.h>

#define N_NODES 100000
#define D_FEAT  64
#define N_EDGES 1600000
#define NPB     128                         // nodes per bucket (dst >> 7)
#define NBUCK   ((N_NODES + NPB - 1) / NPB) // 782
#define NPART   256                         // partition blocks
#define CHUNK   (N_EDGES / NPART)           // 6250 (exact)

// ---------- phase 1: per-chunk histogram over buckets (no global atomics) ----------
__global__ void count_chunks(const int* __restrict__ dst, int* __restrict__ gcount) {
    __shared__ int h[NBUCK];
    for (int i = threadIdx.x; i < NBUCK; i += blockDim.x) h[i] = 0;
    __syncthreads();
    const int beg = blockIdx.x * CHUNK, end = beg + CHUNK;
    for (int i = beg + threadIdx.x; i < end; i += blockDim.x)
        atomicAdd(&h[dst[i] >> 7], 1);
    __syncthreads();
    for (int i = threadIdx.x; i < NBUCK; i += blockDim.x)
        gcount[blockIdx.x * NBUCK + i] = h[i];
}

// ---------- phase 2: bucket totals -> bptr; per-(chunk,bucket) offsets -> goff ----------
__global__ void scan_all(const int* __restrict__ gcount, int* __restrict__ goff,
                         int* __restrict__ bptr, int* __restrict__ row_ptr) {
    __shared__ int tmp[1024];
    const int t = threadIdx.x;
    int tot = 0;
    if (t < NBUCK)
        for (int b = 0; b < NPART; ++b) tot += gcount[b * NBUCK + t];
    tmp[t] = (t < NBUCK) ? tot : 0;
    __syncthreads();
    for (int off = 1; off < 1024; off <<= 1) {
        int v = (t >= off) ? tmp[t - off] : 0;
        __syncthreads();
        tmp[t] += v;
        __syncthreads();
    }
    if (t < NBUCK) {
        int run = tmp[t] - tot;            // exclusive prefix
        bptr[t] = run;
        for (int b = 0; b < NPART; ++b) {
            goff[b * NBUCK + t] = run;
            run += gcount[b * NBUCK + t];
        }
    }
    if (t == 0) {
        bptr[NBUCK] = N_EDGES;
        row_ptr[N_NODES] = N_EDGES;
    }
}

// ---------- phase 3: deterministic partition via LDS cursors ----------
// packed word = src | (dst & 127) << 17   (src < 2^17)
__global__ void partition_chunks(const int* __restrict__ src, const int* __restrict__ dst,
                                 const float* __restrict__ ew, const int* __restrict__ goff,
                                 int2* __restrict__ bedges) {
    __shared__ int cur[NBUCK];
    for (int i = threadIdx.x; i < NBUCK; i += blockDim.x)
        cur[i] = goff[blockIdx.x * NBUCK + i];
    __syncthreads();
    const int beg = blockIdx.x * CHUNK, end = beg + CHUNK;
    for (int i = beg + threadIdx.x; i < end; i += blockDim.x) {
        int d = dst[i];
        int b = d >> 7;
        int p = atomicAdd(&cur[b], 1);     // LDS atomic: ~8 collisions/cursor
        int2 e;
        e.x = src[i] | ((d & (NPB - 1)) << 17);
        e.y = __float_as_int(ew[i]);
        bedges[p] = e;
    }
}

// ---------- phase 4: per-bucket LDS counting sort -> dst-sorted edges + row_ptr ----------
__global__ void sort_bucket(const int2* __restrict__ bedges, const int* __restrict__ bptr,
                            int2* __restrict__ sedges, int* __restrict__ row_ptr) {
    __shared__ int cnt[NPB];
    __shared__ int sc[NPB];
    __shared__ int cur[NPB];
    const int b = blockIdx.x;
    const int t = threadIdx.x;
    const int beg = bptr[b];
    const int end = bptr[b + 1];

    if (t < NPB) cnt[t] = 0;
    __syncthreads();
    for (int i = beg + t; i < end; i += blockDim.x)
        atomicAdd(&cnt[bedges[i].x >> 17], 1);
    __syncthreads();

    if (t < NPB) sc[t] = cnt[t];
    __syncthreads();
    for (int off = 1; off < NPB; off <<= 1) {
        int v = (t >= off && t < NPB) ? sc[t - off] : 0;
        __syncthreads();
        if (t < NPB) sc[t] += v;
        __syncthreads();
    }
    if (t < NPB) {
        int ex = sc[t] - cnt[t];
        cur[t] = ex;
        int node = b * NPB + t;
        if (node < N_NODES) row_ptr[node] = beg + ex;
    }
    __syncthreads();

    for (int i = beg + t; i < end; i += blockDim.x) {
        int2 e = bedges[i];
        int dl = e.x >> 17;
        int p = atomicAdd(&cur[dl], 1);
        int2 o;
        o.x = e.x & 0x1FFFF;
        o.y = e.y;
        sedges[beg + p] = o;
    }
}

// ---------- phase 5: pull SpMM, 8-grouped gathers ----------
// One 64-lane wave per destination node; lane = feature.
// MODE 0: out = X + h (write h) | MODE 1: out += h (write h) | MODE 2: out = (out+h)/4
template <int MODE>
__global__ void spmm_pull(const float* __restrict__ hprev,
                          const int* __restrict__ row_ptr,
                          const int2* __restrict__ edges,
                          float* __restrict__ hout,
                          float* __restrict__ acc,
                          const float* __restrict__ X) {
    int node = blockIdx.x * (blockDim.x >> 6) + (threadIdx.x >> 6);
    int lane = threadIdx.x & 63;
    if (node >= N_NODES) return;

    int beg = row_ptr[node];
    int end = row_ptr[node + 1];

    float a = 0.0f;
    for (int base = beg; base < end; base += 64) {
        int n = end - base;
        if (n > 64) n = 64;
        int s = 0;
        float w = 0.0f;
        if (lane < n) {
            int2 e = edges[base + lane];
            s = e.x;
            w = __int_as_float(e.y);
        }
        for (int j0 = 0; j0 < n; j0 += 8) {
            float t[8], ww[8];
            #pragma unroll
            for (int k = 0; k < 8; ++k) {
                int idx = j0 + k;
                if (idx < n) {                       // wave-uniform
                    int sj = __shfl(s, idx);
                    ww[k]  = __shfl(w, idx);
                    t[k]   = hprev[((size_t)sj << 6) | lane];
                } else {
                    ww[k] = 0.0f; t[k] = 0.0f;
                }
            }
            #pragma unroll
            for (int k = 0; k < 8; ++k)
                a += t[k] * ww[k];
        }
    }

    size_t idx = ((size_t)node << 6) | lane;
    if (MODE == 0) {
        hout[idx] = a;
        acc[idx] = X[idx] + a;
    } else if (MODE == 1) {
        hout[idx] = a;
        acc[idx] += a;
    } else {
        acc[idx] = (acc[idx] + a) * 0.25f;
    }
}

extern "C" void kernel_launch(void* const* d_in, const int* in_sizes, int n_in,
                              void* d_out, int out_size, void* d_ws, size_t ws_size,
                              hipStream_t stream) {
    const float* X   = (const float*)d_in[0];
    const int*   src = (const int*)  d_in[1];
    const int*   dst = (const int*)  d_in[2];
    const float* ew  = (const float*)d_in[3];
    float* out = (float*)d_out;

    const size_t feat = (size_t)N_NODES * D_FEAT;

    char* p = (char*)d_ws;
    float* hA      = (float*)p;  p += feat * sizeof(float);        // 25.6 MB
    float* hB      = (float*)p;  p += feat * sizeof(float);        // 25.6 MB
    int2*  bedges  = (int2*)p;   p += (size_t)N_EDGES * 8;         // 12.8 MB
    int2*  sedges  = (int2*)p;   p += (size_t)N_EDGES * 8;         // 12.8 MB
    int*   bptr    = (int*)p;    p += ((size_t)NBUCK + 1) * 4;
    int*   row_ptr = (int*)p;    p += ((size_t)N_NODES + 1) * 4;

    // gcount/goff alias hA's space: dead before spmm<0> writes hA
    int* gcount = (int*)hA;                       // 256*782*4 = 0.8 MB
    int* goff   = gcount + (size_t)NPART * NBUCK; // 0.8 MB

    count_chunks<<<NPART, 256, 0, stream>>>(dst, gcount);
    scan_all<<<1, 1024, 0, stream>>>(gcount, goff, bptr, row_ptr);
    partition_chunks<<<NPART, 256, 0, stream>>>(src, dst, ew, goff, bedges);
    sort_bucket<<<NBUCK, 256, 0, stream>>>(bedges, bptr, sedges, row_ptr);

    const int nblk = (N_NODES + 3) / 4;   // 4 waves/block
    spmm_pull<0><<<nblk, 256, 0, stream>>>(X,  row_ptr, sedges, hA, out, X);
    spmm_pull<1><<<nblk, 256, 0, stream>>>(hA, row_ptr, sedges, hB, out, X);
    spmm_pull<2><<<nblk, 256, 0, stream>>>(hB, row_ptr, sedges, (float*)nullptr, out, X);
}

// Round 6
// 333.597 us; speedup vs baseline: 7.5306x; 1.4329x over previous
//
#include <hip/hip_runtime.h>

#define N_NODES 100000
#define D_FEAT  64
#define N_EDGES 1600000
#define NPB     128                         // nodes per bucket (dst >> 7)
#define NBUCK   ((N_NODES + NPB - 1) / NPB) // 782
#define NPART   512                         // partition chunks
#define CHUNK   (N_EDGES / NPART)           // 3125 (exact)

// ---------- phase 1: per-chunk histogram over buckets ----------
__global__ void count_chunks(const int* __restrict__ dst, int* __restrict__ gcount) {
    __shared__ int h[NBUCK];
    for (int i = threadIdx.x; i < NBUCK; i += blockDim.x) h[i] = 0;
    __syncthreads();
    const int beg = blockIdx.x * CHUNK, end = beg + CHUNK;
    for (int i = beg + threadIdx.x; i < end; i += blockDim.x)
        atomicAdd(&h[dst[i] >> 7], 1);
    __syncthreads();
    for (int i = threadIdx.x; i < NBUCK; i += blockDim.x)
        gcount[blockIdx.x * NBUCK + i] = h[i];
}

// ---------- phase 2a: per-bucket scan over the 512 chunks (one block per bucket) ----------
__global__ __launch_bounds__(NPART) void scan_chunks(const int* __restrict__ gcount,
                                                     int* __restrict__ goff,
                                                     int* __restrict__ tot) {
    __shared__ int tmp[NPART];
    const int t = threadIdx.x;      // chunk id
    const int b = blockIdx.x;       // bucket id
    int v = gcount[t * NBUCK + b];
    tmp[t] = v;
    __syncthreads();
    for (int off = 1; off < NPART; off <<= 1) {
        int u = (t >= off) ? tmp[t - off] : 0;
        __syncthreads();
        tmp[t] += u;
        __syncthreads();
    }
    goff[t * NBUCK + b] = tmp[t] - v;           // exclusive within bucket
    if (t == NPART - 1) tot[b] = tmp[t];        // bucket total
}

// ---------- phase 2b: scan 782 bucket totals -> bptr ----------
__global__ void scan_tot(const int* __restrict__ tot, int* __restrict__ bptr,
                         int* __restrict__ row_ptr) {
    __shared__ int tmp[1024];
    const int t = threadIdx.x;
    int v = (t < NBUCK) ? tot[t] : 0;
    tmp[t] = v;
    __syncthreads();
    for (int off = 1; off < 1024; off <<= 1) {
        int u = (t >= off) ? tmp[t - off] : 0;
        __syncthreads();
        tmp[t] += u;
        __syncthreads();
    }
    if (t < NBUCK) bptr[t] = tmp[t] - v;
    if (t == 0) {
        bptr[NBUCK] = N_EDGES;
        row_ptr[N_NODES] = N_EDGES;
    }
}

// ---------- phase 3: deterministic partition via LDS cursors ----------
// packed word = src | (dst & 127) << 17   (src < 2^17)
__global__ void partition_chunks(const int* __restrict__ src, const int* __restrict__ dst,
                                 const float* __restrict__ ew, const int* __restrict__ goff,
                                 const int* __restrict__ bptr, int2* __restrict__ bedges) {
    __shared__ int cur[NBUCK];
    for (int i = threadIdx.x; i < NBUCK; i += blockDim.x)
        cur[i] = goff[blockIdx.x * NBUCK + i] + bptr[i];
    __syncthreads();
    const int beg = blockIdx.x * CHUNK, end = beg + CHUNK;
    for (int i = beg + threadIdx.x; i < end; i += blockDim.x) {
        int d = dst[i];
        int b = d >> 7;
        int p = atomicAdd(&cur[b], 1);
        int2 e;
        e.x = src[i] | ((d & (NPB - 1)) << 17);
        e.y = __float_as_int(ew[i]);
        bedges[p] = e;
    }
}

// ---------- phase 4: per-bucket LDS counting sort -> dst-sorted edges + row_ptr ----------
__global__ void sort_bucket(const int2* __restrict__ bedges, const int* __restrict__ bptr,
                            int2* __restrict__ sedges, int* __restrict__ row_ptr) {
    __shared__ int cnt[NPB];
    __shared__ int sc[NPB];
    __shared__ int cur[NPB];
    const int b = blockIdx.x;
    const int t = threadIdx.x;
    const int beg = bptr[b];
    const int end = bptr[b + 1];

    if (t < NPB) cnt[t] = 0;
    __syncthreads();
    for (int i = beg + t; i < end; i += blockDim.x)
        atomicAdd(&cnt[bedges[i].x >> 17], 1);
    __syncthreads();

    if (t < NPB) sc[t] = cnt[t];
    __syncthreads();
    for (int off = 1; off < NPB; off <<= 1) {
        int v = (t >= off && t < NPB) ? sc[t - off] : 0;
        __syncthreads();
        if (t < NPB) sc[t] += v;
        __syncthreads();
    }
    if (t < NPB) {
        int ex = sc[t] - cnt[t];
        cur[t] = ex;
        int node = b * NPB + t;
        if (node < N_NODES) row_ptr[node] = beg + ex;
    }
    __syncthreads();

    for (int i = beg + t; i < end; i += blockDim.x) {
        int2 e = bedges[i];
        int dl = e.x >> 17;
        int p = atomicAdd(&cur[dl], 1);
        int2 o;
        o.x = e.x & 0x1FFFF;
        o.y = e.y;
        sedges[beg + p] = o;
    }
}

// ---------- phase 5: pull SpMM — scalar edge stream + 16-wide gather batches ----------
// One 64-lane wave per destination node; lane = feature.
// Edge indices are wave-uniform -> readfirstlane forces row range into SGPRs so
// edges[j+k] compiles to s_load (scalar pipe, K$), no shfl, no vector edge loads.
// MODE 0/1: hout = a | MODE 2: out = (X + h1 + h2 + a) * 0.25
template <int MODE>
__global__ __launch_bounds__(256) void spmm_pull(const float* __restrict__ hprev,
                                                 const int* __restrict__ row_ptr,
                                                 const int2* __restrict__ edges,
                                                 float* __restrict__ hout,
                                                 float* __restrict__ out,
                                                 const float* __restrict__ X,
                                                 const float* __restrict__ h1,
                                                 const float* __restrict__ h2) {
    int node = blockIdx.x * 4 + (threadIdx.x >> 6);
    int lane = threadIdx.x & 63;
    if (node >= N_NODES) return;

    int beg = __builtin_amdgcn_readfirstlane(row_ptr[node]);
    int end = __builtin_amdgcn_readfirstlane(row_ptr[node + 1]);

    float a = 0.0f;
    for (int j = beg; j < end; j += 16) {
        float t[16], w[16];
        #pragma unroll
        for (int k = 0; k < 16; ++k) {
            int jk = j + k;
            int idx = (jk < end) ? jk : beg;      // clamp (branch-free, scalar)
            int2 e = edges[idx];                  // s_load: uniform addr
            w[k] = (jk < end) ? __int_as_float(e.y) : 0.0f;
            t[k] = hprev[((size_t)e.x << 6) | lane];
        }
        #pragma unroll
        for (int k = 0; k < 16; ++k)
            a += t[k] * w[k];
    }

    size_t idx = ((size_t)node << 6) | lane;
    if (MODE == 2)
        out[idx] = (X[idx] + h1[idx] + h2[idx] + a) * 0.25f;
    else
        hout[idx] = a;
}

extern "C" void kernel_launch(void* const* d_in, const int* in_sizes, int n_in,
                              void* d_out, int out_size, void* d_ws, size_t ws_size,
                              hipStream_t stream) {
    const float* X   = (const float*)d_in[0];
    const int*   src = (const int*)  d_in[1];
    const int*   dst = (const int*)  d_in[2];
    const float* ew  = (const float*)d_in[3];
    float* out = (float*)d_out;

    const size_t feat = (size_t)N_NODES * D_FEAT;

    char* p = (char*)d_ws;
    float* hA      = (float*)p;  p += feat * sizeof(float);        // 25.6 MB
    float* hB      = (float*)p;  p += feat * sizeof(float);        // 25.6 MB
    int2*  bedges  = (int2*)p;   p += (size_t)N_EDGES * 8;         // 12.8 MB
    int2*  sedges  = (int2*)p;   p += (size_t)N_EDGES * 8;         // 12.8 MB
    int*   bptr    = (int*)p;    p += ((size_t)NBUCK + 1) * 4;
    int*   row_ptr = (int*)p;    p += ((size_t)N_NODES + 1) * 4;
    int*   tot     = (int*)p;    p += (size_t)NBUCK * 4;

    // gcount/goff alias hA's space: dead before spmm<0> writes hA
    int* gcount = (int*)hA;                       // 512*782*4 = 1.6 MB
    int* goff   = gcount + (size_t)NPART * NBUCK; // 1.6 MB

    count_chunks   <<<NPART, 256, 0, stream>>>(dst, gcount);
    scan_chunks    <<<NBUCK, NPART, 0, stream>>>(gcount, goff, tot);
    scan_tot       <<<1, 1024, 0, stream>>>(tot, bptr, row_ptr);
    partition_chunks<<<NPART, 256, 0, stream>>>(src, dst, ew, goff, bptr, bedges);
    sort_bucket    <<<NBUCK, 256, 0, stream>>>(bedges, bptr, sedges, row_ptr);

    const int nblk = (N_NODES + 3) / 4;   // 4 waves/block
    spmm_pull<0><<<nblk, 256, 0, stream>>>(X,  row_ptr, sedges, hA, out, X, hA, hB);
    spmm_pull<1><<<nblk, 256, 0, stream>>>(hA, row_ptr, sedges, hB, out, X, hA, hB);
    spmm_pull<2><<<nblk, 256, 0, stream>>>(hB, row_ptr, sedges, (float*)nullptr, out, X, hA, hB);
}